// Round 9
// baseline (152.350 us; speedup 1.0000x reference)
//
#include <hip/hip_runtime.h>
#include <hip/hip_bf16.h>

// Problem constants
#define BATCH 4
#define TSEQ  2048
#define CDIM  768
#define HNUM  12
#define DHEAD 64
#define NQKV  (3*CDIM)          // 2304
#define BTOT  (BATCH*TSEQ)      // 8192
#define BH    (BATCH*HNUM)      // 48

typedef unsigned short u16;
typedef __attribute__((ext_vector_type(8))) __bf16 bf16x8;
typedef __attribute__((ext_vector_type(4))) float f32x4;

#define MFMA16(a,b,c) __builtin_amdgcn_mfma_f32_16x16x32_bf16((a),(b),(c),0,0,0)

// fp32 -> bf16 RNE (hand-rolled, version-independent)
__device__ __forceinline__ u16 f2b(float f) {
    union { float f; unsigned u; } v; v.f = f;
    unsigned u = v.u;
    unsigned r = (u + 0x7fffu + ((u >> 16) & 1u)) >> 16;
    return (u16)r;
}

// pack 2 fp32 -> 2 bf16 in one u32 (lo -> bits 15:0), RNE
__device__ __forceinline__ unsigned cvtpk(float lo, float hi) {
    unsigned r;
    asm("v_cvt_pk_bf16_f32 %0, %1, %2" : "=v"(r) : "v"(lo), "v"(hi));
    return r;
}

// raw 2^x
__device__ __forceinline__ float fexp2(float x) {
    float r;
    asm("v_exp_f32 %0, %1" : "=v"(r) : "v"(x));
    return r;
}

__device__ __forceinline__ void gload_lds(const void* g, void* l) {
    __builtin_amdgcn_global_load_lds(
        (const __attribute__((address_space(1))) void*)g,
        (__attribute__((address_space(3))) void*)l, 16, 0, 0);
}

// ---------------- elementwise cast fp32 -> bf16 ----------------
__global__ __launch_bounds__(256) void cast_f32_bf16(
        const float* __restrict__ in, u16* __restrict__ out, int n4) {
    int i = blockIdx.x * blockDim.x + threadIdx.x;
    if (i >= n4) return;
    float4 a = reinterpret_cast<const float4*>(in)[i];
    ushort4 o;
    o.x = f2b(a.x); o.y = f2b(a.y); o.z = f2b(a.z); o.w = f2b(a.w);
    reinterpret_cast<ushort4*>(out)[i] = o;
}

// ---------------- transpose + cast: in[R][Cc] fp32 -> out[Cc][R] bf16 ----------------
__global__ __launch_bounds__(256) void tcast(
        const float* __restrict__ in, u16* __restrict__ out, int R, int Cc) {
    __shared__ float tile[32][33];
    int c0 = blockIdx.x * 32, r0 = blockIdx.y * 32;
    int tx = threadIdx.x, ty = threadIdx.y;   // block (32,8)
    #pragma unroll
    for (int i = 0; i < 32; i += 8)
        tile[ty + i][tx] = in[(size_t)(r0 + ty + i) * Cc + c0 + tx];
    __syncthreads();
    #pragma unroll
    for (int i = 0; i < 32; i += 8)
        out[(size_t)(c0 + ty + i) * R + r0 + tx] = f2b(tile[tx][ty + i]);
}

// ---------------- GEMM1: QKV projection, BM=128 BN=256, 4 waves x (128x64) ----
// Intensity 42.7 FLOP/LDS-byte (vs 32 for 64x64 wave-tiles). 3-buffer ring,
// 2-ahead staging, counted vmcnt(6). Slot-XOR LDS swizzle (rule #21: source
// pre-swizzled, reads XOR the same involution) -> 2-way banks (free).
// Swapped-operand MFMA: acc[m][n] = C^T fragment; j walks 4 consecutive
// channels -> packed ushort4 stores for q/k.
template<int NX>
__global__ __launch_bounds__(256, 2) void gemm_qkv(
        const u16* __restrict__ A, const u16* __restrict__ Bt,
        const float* __restrict__ bias,
        u16* __restrict__ qb, u16* __restrict__ kb, u16* __restrict__ vtb,
        int K) {
    __shared__ u16 sA[3][128 * 32];
    __shared__ u16 sB[3][256 * 32];
    const int tid = threadIdx.x;
    const int lane = tid & 63;
    const int w = tid >> 6;                     // 0..3, wave owns cols w*64..
    const int g = lane >> 4, lr = lane & 15;
    const int cpx = gridDim.x >> 3;
    const int wg = ((int)blockIdx.x & 7) * cpx + ((int)blockIdx.x >> 3);
    const int bx = wg % NX, by = wg / NX;
    const int m0 = by * 128, n0 = bx * 256;

    f32x4 acc[8][4] = {};

    auto stage = [&](int buf, int kt) {
        #pragma unroll
        for (int i = 0; i < 2; ++i) {           // A: 128x32 = 512 chunks
            int c = i * 256 + tid, r = c >> 2, s = c & 3;
            int c8 = s ^ ((r >> 1) & 3);        // pre-swizzled source slot
            gload_lds(A + (size_t)(m0 + r) * K + kt * 32 + c8 * 8, &sA[buf][c * 8]);
        }
        #pragma unroll
        for (int i = 0; i < 4; ++i) {           // B: 256x32 = 1024 chunks
            int c = i * 256 + tid, r = c >> 2, s = c & 3;
            int c8 = s ^ ((r >> 1) & 3);
            gload_lds(Bt + (size_t)(n0 + r) * K + kt * 32 + c8 * 8, &sB[buf][c * 8]);
        }
    };

    const int KT = K / 32;                      // 24
    stage(0, 0); stage(1, 1);                   // 12 loads in flight / thread
    for (int kt = 0; kt < KT; ++kt) {
        if (kt + 1 < KT) asm volatile("s_waitcnt vmcnt(6)" ::: "memory");
        else             asm volatile("s_waitcnt vmcnt(0)" ::: "memory");
        __builtin_amdgcn_s_barrier();           // tile kt fully in LDS
        if (kt + 2 < KT) stage((kt + 2) % 3, kt + 2);
        const u16* cA = sA[kt % 3];
        const u16* cB = sB[kt % 3];
        bf16x8 af[8], bfr[4];
        #pragma unroll
        for (int m = 0; m < 8; ++m) {
            int r = m * 16 + lr;
            af[m] = *(const bf16x8*)&cA[r * 32 + ((g ^ ((r >> 1) & 3)) << 3)];
        }
        #pragma unroll
        for (int n = 0; n < 4; ++n) {
            int r = w * 64 + n * 16 + lr;
            bfr[n] = *(const bf16x8*)&cB[r * 32 + ((g ^ ((r >> 1) & 3)) << 3)];
        }
        __builtin_amdgcn_s_setprio(1);
        #pragma unroll
        for (int m = 0; m < 8; ++m)
            #pragma unroll
            for (int n = 0; n < 4; ++n)
                acc[m][n] = MFMA16(bfr[n], af[m], acc[m][n]);   // C^T tile
        __builtin_amdgcn_s_setprio(0);
    }

    // Epilogue: D row = channel (w*64 + n*16 + g*4 + j), D col = token (m*16+lr)
    const int which = n0 / CDIM;                // 0=q 1=k 2=v, uniform per block
    #pragma unroll
    for (int m = 0; m < 8; ++m) {
        const int rg = m0 + m * 16 + lr;
        const int b = rg >> 11, t = rg & (TSEQ - 1);
        #pragma unroll
        for (int n = 0; n < 4; ++n) {
            const int cg = n0 + w * 64 + n * 16 + (g << 2);
            const int c  = cg - which * CDIM;
            const int h  = c >> 6, d = c & 63;
            const size_t bh = (size_t)(b * HNUM + h);
            const float4 bv = *(const float4*)&bias[cg];
            const float v0 = acc[m][n][0] + bv.x;
            const float v1 = acc[m][n][1] + bv.y;
            const float v2 = acc[m][n][2] + bv.z;
            const float v3 = acc[m][n][3] + bv.w;
            if (which == 0) {
                const float s = 0.1803368801111243f;   // 0.125 * log2(e)
                ushort4 pv;
                pv.x = f2b(v0 * s); pv.y = f2b(v1 * s);
                pv.z = f2b(v2 * s); pv.w = f2b(v3 * s);
                *(ushort4*)&qb[(bh * TSEQ + t) * DHEAD + d] = pv;
            } else if (which == 1) {
                ushort4 pv;
                pv.x = f2b(v0); pv.y = f2b(v1); pv.z = f2b(v2); pv.w = f2b(v3);
                *(ushort4*)&kb[(bh * TSEQ + t) * DHEAD + d] = pv;
            } else {
                vtb[(bh * DHEAD + d + 0) * TSEQ + t] = f2b(v0);
                vtb[(bh * DHEAD + d + 1) * TSEQ + t] = f2b(v1);
                vtb[(bh * DHEAD + d + 2) * TSEQ + t] = f2b(v2);
                vtb[(bh * DHEAD + d + 3) * TSEQ + t] = f2b(v3);
            }
        }
    }
}

// ---------------- GEMM2: out projection (unchanged 128^2 3-ring kernel) -----
template<int NX>
__global__ __launch_bounds__(256) void gemm_out(
        const u16* __restrict__ A, const u16* __restrict__ Bt,
        const float* __restrict__ bias, float* __restrict__ outf, int K) {
    __shared__ u16 sA[3][128 * 32];
    __shared__ u16 sB[3][128 * 32];
    const int tid = threadIdx.x;
    const int lane = tid & 63;
    const int w = tid >> 6;
    const int wr = w >> 1, wc = w & 1;
    const int cpx = gridDim.x >> 3;
    const int wg = ((int)blockIdx.x & 7) * cpx + ((int)blockIdx.x >> 3);
    const int bx = wg % NX, by = wg / NX;
    const int m0 = by * 128, n0 = bx * 128;

    f32x4 acc[4][4] = {};

    auto stage = [&](int buf, int kt) {
        #pragma unroll
        for (int i = 0; i < 2; ++i) {
            int chunk = i * 256 + tid;
            int row = chunk >> 2, c8 = chunk & 3;
            gload_lds(A  + (size_t)(m0 + row) * K + kt * 32 + c8 * 8, &sA[buf][chunk * 8]);
            gload_lds(Bt + (size_t)(n0 + row) * K + kt * 32 + c8 * 8, &sB[buf][chunk * 8]);
        }
    };

    const int KT = K / 32;
    stage(0, 0); stage(1, 1);
    for (int kt = 0; kt < KT; ++kt) {
        if (kt + 1 < KT) asm volatile("s_waitcnt vmcnt(4)" ::: "memory");
        else             asm volatile("s_waitcnt vmcnt(0)" ::: "memory");
        __builtin_amdgcn_s_barrier();
        if (kt + 2 < KT) stage((kt + 2) % 3, kt + 2);
        const u16* cA = sA[kt % 3];
        const u16* cB = sB[kt % 3];
        bf16x8 af[4], bfr[4];
        #pragma unroll
        for (int m = 0; m < 4; ++m)
            af[m] = *(const bf16x8*)&cA[(wr * 64 + m * 16 + (lane & 15)) * 32 + ((lane >> 4) << 3)];
        #pragma unroll
        for (int n = 0; n < 4; ++n)
            bfr[n] = *(const bf16x8*)&cB[(wc * 64 + n * 16 + (lane & 15)) * 32 + ((lane >> 4) << 3)];
        #pragma unroll
        for (int m = 0; m < 4; ++m)
            #pragma unroll
            for (int n = 0; n < 4; ++n)
                acc[m][n] = MFMA16(bfr[n], af[m], acc[m][n]);   // C^T tile
    }

    #pragma unroll
    for (int m = 0; m < 4; ++m) {
        const int rg = m0 + wr * 64 + m * 16 + (lane & 15);
        #pragma unroll
        for (int n = 0; n < 4; ++n) {
            const int cg = n0 + wc * 64 + n * 16 + ((lane >> 4) << 2);
            const float4 bv = *(const float4*)&bias[cg];
            float4 ov;
            ov.x = acc[m][n][0] + bv.x;
            ov.y = acc[m][n][1] + bv.y;
            ov.z = acc[m][n][2] + bv.z;
            ov.w = acc[m][n][3] + bv.w;
            *(float4*)&outf[(size_t)rg * CDIM + cg] = ov;
        }
    }
}

// ---------------- causal flash attention ----------------
// 1536 blocks (32 q-tiles x 48 bh), LONGEST FIRST. 256 threads = 4 waves,
// each wave owns 16 q rows of a 64-row q-tile. KVBLK=64 double-buffered.
// Swapped QK^T (S^T: q=lane&15, k=n*16+g*4+j), in-register P, defer-max
// (THR=8, exp2 domain), row-sum via MFMA-with-ones (O-layout ls), setprio.
__global__ __launch_bounds__(256, 4) void attn_fwd(
        const u16* __restrict__ qb, const u16* __restrict__ kb,
        const u16* __restrict__ vtb, u16* __restrict__ yb) {
    __shared__ u16 sK[2][64 * 64];
    __shared__ u16 sVt[2][64 * 64];
    const int qt = 31 - (int)(blockIdx.x / BH);  // 64-row q-tile, longest first
    const int bh = blockIdx.x % BH;
    const int b = bh / HNUM, h = bh % HNUM;
    const int tid = threadIdx.x, lane = tid & 63, w = tid >> 6;   // w 0..3
    const int g = lane >> 4, lq = lane & 15;
    const int qlo = qt * 64 + w * 16;            // wave's 16 q rows
    const u16* qbase = qb  + (size_t)bh * TSEQ * DHEAD;
    const u16* kbase = kb  + (size_t)bh * TSEQ * DHEAD;
    const u16* vbase = vtb + (size_t)bh * DHEAD * TSEQ;

    // Q fragment (B-operand): Q[qlo+lq][ks*32 + g*8 + e] (scale pre-folded)
    bf16x8 qf[2];
    #pragma unroll
    for (int ks = 0; ks < 2; ++ks)
        qf[ks] = *(const bf16x8*)&qbase[(size_t)(qlo + lq) * DHEAD + ks * 32 + g * 8];

    // all-ones bf16 B-fragment for the row-sum MFMA
    union { unsigned u[4]; bf16x8 v; } ones;
    #pragma unroll
    for (int i = 0; i < 4; ++i) ones.u[i] = 0x3f803f80u;

    f32x4 o[4] = {};
    f32x4 ls = {};                               // row sums, O-layout (q=g*4+j)
    float mx = -__builtin_inff();

    // staging: 2 chunks of K + 2 of Vt per thread (swizzled source, linear dest)
    auto STAGE = [&](int buf, int kt) {
        const int k0 = kt << 6;
        #pragma unroll
        for (int i = 0; i < 2; ++i) {
            int chunk = i * 256 + tid;           // 512 chunks of 16B per tile
            int srow = chunk >> 3;
            int cb = ((chunk & 7) << 4) ^ ((srow & 7) << 4);   // logical byte col
            gload_lds(kbase + (size_t)(k0 + srow) * DHEAD + (cb >> 1), &sK[buf][chunk * 8]);
            gload_lds(vbase + (size_t)srow * TSEQ + k0 + (cb >> 1),    &sVt[buf][chunk * 8]);
        }
    };

    const int nk = qt + 1;
    STAGE(0, 0);
    __syncthreads();
    for (int kt = 0; kt < nk; ++kt) {
        const int k0 = kt << 6;
        if (kt + 1 < nk) STAGE((kt + 1) & 1, kt + 1);   // prefetch overlaps compute
        const u16* cK = sK[kt & 1];
        const u16* cV = sVt[kt & 1];
        // S^T = K Q^T : lane holds q=lq, kpos = k0 + n*16 + g*4 + j
        f32x4 s[4];
        #pragma unroll
        for (int n = 0; n < 4; ++n) s[n] = f32x4{0.f, 0.f, 0.f, 0.f};
        __builtin_amdgcn_s_setprio(1);
        #pragma unroll
        for (int n = 0; n < 4; ++n) {
            #pragma unroll
            for (int ks = 0; ks < 2; ++ks) {
                int r = n * 16 + lq;
                int lb = (r * 128 + (ks * 32 + g * 8) * 2) ^ ((r & 7) << 4);
                bf16x8 kf = *(const bf16x8*)((const char*)cK + lb);
                s[n] = MFMA16(kf, qf[ks], s[n]);
            }
        }
        __builtin_amdgcn_s_setprio(0);
        // causal mask (only near-diagonal tiles)
        if (k0 + 63 > qlo) {
            const int qa = qlo + lq;
            #pragma unroll
            for (int n = 0; n < 4; ++n)
                #pragma unroll
                for (int j = 0; j < 4; ++j)
                    if (k0 + n * 16 + g * 4 + j > qa) s[n][j] = -__builtin_inff();
        }
        // row max (row q=lq): 15 in-lane + 2 cross-group shfls
        float t0 = fmaxf(fmaxf(s[0][0], s[0][1]), fmaxf(s[0][2], s[0][3]));
        float t1 = fmaxf(fmaxf(s[1][0], s[1][1]), fmaxf(s[1][2], s[1][3]));
        float t2 = fmaxf(fmaxf(s[2][0], s[2][1]), fmaxf(s[2][2], s[2][3]));
        float t3 = fmaxf(fmaxf(s[3][0], s[3][1]), fmaxf(s[3][2], s[3][3]));
        float tmax = fmaxf(fmaxf(t0, t1), fmaxf(t2, t3));
        tmax = fmaxf(tmax, __shfl_xor(tmax, 16));
        tmax = fmaxf(tmax, __shfl_xor(tmax, 32));
        // defer-max: rescale only if some row grew past THR=8 (exp2 units)
        if (__any(tmax > mx + 8.0f)) {
            float mnew = fmaxf(mx, tmax);
            float sc = fexp2(mx - mnew);
            mx = mnew;
            #pragma unroll
            for (int j = 0; j < 4; ++j) {
                float scj = __shfl(sc, (lane & 48) | ((g << 2) + j));
                ls[j] *= scj;
                #pragma unroll
                for (int n = 0; n < 4; ++n) o[n][j] *= scj;
            }
        }
        #pragma unroll
        for (int n = 0; n < 4; ++n)
            #pragma unroll
            for (int j = 0; j < 4; ++j)
                s[n][j] = fexp2(s[n][j] - mx);
        // pack P to bf16 pairs (k ascending within u32)
        unsigned apk[4], bpk[4];
        #pragma unroll
        for (int n = 0; n < 4; ++n) {
            apk[n] = cvtpk(s[n][0], s[n][1]);
            bpk[n] = cvtpk(s[n][2], s[n][3]);
        }
        // PV: redistribute P into A-frag layout via shfl, then MFMA.
        // Row sums ride the matrix pipe: ls += pa * ones.
        const int s0l = lq + ((lane & 16) << 1);
        const bool hi = (lane & 32) != 0;
        #pragma unroll
        for (int ks = 0; ks < 2; ++ks) {
            unsigned A0  = (unsigned)__shfl((int)apk[2 * ks],     s0l);
            unsigned B0  = (unsigned)__shfl((int)bpk[2 * ks],     s0l);
            unsigned A1  = (unsigned)__shfl((int)apk[2 * ks + 1], s0l);
            unsigned B1  = (unsigned)__shfl((int)bpk[2 * ks + 1], s0l);
            unsigned A0h = (unsigned)__shfl((int)apk[2 * ks],     s0l + 16);
            unsigned B0h = (unsigned)__shfl((int)bpk[2 * ks],     s0l + 16);
            unsigned A1h = (unsigned)__shfl((int)apk[2 * ks + 1], s0l + 16);
            unsigned B1h = (unsigned)__shfl((int)bpk[2 * ks + 1], s0l + 16);
            union { unsigned u[4]; bf16x8 v; } pa;
            pa.u[0] = hi ? A1  : A0;
            pa.u[1] = hi ? B1  : B0;
            pa.u[2] = hi ? A1h : A0h;
            pa.u[3] = hi ? B1h : B0h;
            __builtin_amdgcn_s_setprio(1);
            #pragma unroll
            for (int n = 0; n < 4; ++n) {
                int d = n * 16 + lq;
                int lb = (d * 128 + (ks * 32 + g * 8) * 2) ^ ((d & 7) << 4);
                bf16x8 vf = *(const bf16x8*)((const char*)cV + lb);
                o[n] = MFMA16(pa.v, vf, o[n]);
            }
            ls = MFMA16(pa.v, ones.v, ls);
            __builtin_amdgcn_s_setprio(0);
        }
        __syncthreads();
    }

    // epilogue: y[b, t, h*64 + d] bf16 ; O rows q = g*4+j; ls already O-layout
    #pragma unroll
    for (int j = 0; j < 4; ++j) {
        float inv = 1.f / ls[j];
        const int t = qlo + g * 4 + j;
        #pragma unroll
        for (int n = 0; n < 4; ++n) {
            const int c = h * DHEAD + n * 16 + lq;
            yb[((size_t)b * TSEQ + t) * CDIM + c] = f2b(o[n][j] * inv);
        }
    }
}

extern "C" void kernel_launch(void* const* d_in, const int* in_sizes, int n_in,
                              void* d_out, int out_size, void* d_ws, size_t ws_size,
                              hipStream_t stream) {
    const float* x      = (const float*)d_in[0];
    const float* W_attn = (const float*)d_in[1];
    const float* b_attn = (const float*)d_in[2];
    const float* W_proj = (const float*)d_in[3];
    const float* b_proj = (const float*)d_in[4];
    float* out = (float*)d_out;

    // workspace layout (bf16 = u16). yb aliases xb (xb dead after GEMM1).
    u16* ws = (u16*)d_ws;
    u16* xb     = ws;                                   // [BTOT][CDIM]
    u16* yb     = xb;                                   // [BTOT][CDIM] (alias)
    u16* WattnT = xb     + (size_t)BTOT * CDIM;         // [NQKV][CDIM]
    u16* WprojT = WattnT + (size_t)NQKV * CDIM;         // [CDIM][CDIM]
    u16* qb     = WprojT + (size_t)CDIM * CDIM;         // [BH][TSEQ][DHEAD]
    u16* kb     = qb     + (size_t)BH * TSEQ * DHEAD;
    u16* vtb    = kb     + (size_t)BH * TSEQ * DHEAD;   // [BH][DHEAD][TSEQ]

    // 1) casts / transposes
    int n4 = BTOT * CDIM / 4;
    cast_f32_bf16<<<(n4 + 255) / 256, 256, 0, stream>>>(x, xb, n4);
    tcast<<<dim3(NQKV / 32, CDIM / 32), dim3(32, 8), 0, stream>>>(W_attn, WattnT, CDIM, NQKV);
    tcast<<<dim3(CDIM / 32, CDIM / 32), dim3(32, 8), 0, stream>>>(W_proj, WprojT, CDIM, CDIM);

    // 2) QKV projection + scatter (576 blocks of 128x256, XCD-swizzled)
    gemm_qkv<NQKV / 256><<<dim3((NQKV / 256) * (BTOT / 128)), 256, 0, stream>>>(
        xb, WattnT, b_attn, qb, kb, vtb, CDIM);

    // 3) causal flash attention (fine-grained LPT: 64-row q-tiles, longest first)
    attn_fwd<<<dim3((TSEQ / 64) * BH), 256, 0, stream>>>(qb, kb, vtb, yb);

    // 4) output projection (384 blocks, XCD-swizzled)
    gemm_out<CDIM / 128><<<dim3((CDIM / 128) * (BTOT / 128)), 256, 0, stream>>>(
        yb, WprojT, b_proj, out, CDIM);
}

// Round 10
// 142.488 us; speedup vs baseline: 1.0692x; 1.0692x over previous
//
#include <hip/hip_runtime.h>
#include <hip/hip_bf16.h>

// Problem constants
#define BATCH 4
#define TSEQ  2048
#define CDIM  768
#define HNUM  12
#define DHEAD 64
#define NQKV  (3*CDIM)          // 2304
#define BTOT  (BATCH*TSEQ)      // 8192
#define BH    (BATCH*HNUM)      // 48

typedef unsigned short u16;
typedef __attribute__((ext_vector_type(8))) __bf16 bf16x8;
typedef __attribute__((ext_vector_type(4))) float f32x4;

#define MFMA16(a,b,c) __builtin_amdgcn_mfma_f32_16x16x32_bf16((a),(b),(c),0,0,0)

// fp32 -> bf16 RNE (hand-rolled, version-independent)
__device__ __forceinline__ u16 f2b(float f) {
    union { float f; unsigned u; } v; v.f = f;
    unsigned u = v.u;
    unsigned r = (u + 0x7fffu + ((u >> 16) & 1u)) >> 16;
    return (u16)r;
}

// pack 2 fp32 -> 2 bf16 in one u32 (lo -> bits 15:0), RNE
__device__ __forceinline__ unsigned cvtpk(float lo, float hi) {
    unsigned r;
    asm("v_cvt_pk_bf16_f32 %0, %1, %2" : "=v"(r) : "v"(lo), "v"(hi));
    return r;
}

// raw 2^x
__device__ __forceinline__ float fexp2(float x) {
    float r;
    asm("v_exp_f32 %0, %1" : "=v"(r) : "v"(x));
    return r;
}

__device__ __forceinline__ void gload_lds(const void* g, void* l) {
    __builtin_amdgcn_global_load_lds(
        (const __attribute__((address_space(1))) void*)g,
        (__attribute__((address_space(3))) void*)l, 16, 0, 0);
}

// ---------------- weight transpose+cast (both weights, one launch) ----------
// W_attn [768][2304] -> WaT [2304][768] bf16 : blockIdx.x in [0,72)
// W_proj [768][ 768] -> WpT [ 768][768] bf16 : blockIdx.x in [72,96)
__global__ __launch_bounds__(256) void tcast2(
        const float* __restrict__ Wa, const float* __restrict__ Wp,
        u16* __restrict__ WaT, u16* __restrict__ WpT) {
    __shared__ float tile[32][33];
    const float* in; u16* out; int Cc; int bx = blockIdx.x;
    if (bx < NQKV / 32) { in = Wa; out = WaT; Cc = NQKV; }
    else                { in = Wp; out = WpT; Cc = CDIM; bx -= NQKV / 32; }
    int c0 = bx * 32, r0 = blockIdx.y * 32;
    int tx = threadIdx.x, ty = threadIdx.y;   // block (32,8)
    #pragma unroll
    for (int i = 0; i < 32; i += 8)
        tile[ty + i][tx] = in[(size_t)(r0 + ty + i) * Cc + c0 + tx];
    __syncthreads();
    #pragma unroll
    for (int i = 0; i < 32; i += 8)
        out[(size_t)(c0 + ty + i) * CDIM + r0 + tx] = f2b(tile[tx][ty + i]);
}

// ---------------- GEMM1: QKV projection with FUSED x-cast --------------------
// A staged as fp32 directly from x via global_load_lds (2-buf, 48 KB LDS,
// R6 cadence: stage(kt+1) -> compute(kt) -> syncthreads). A-slot XOR swizzle
// p = l ^ (r&7) (both-sides involution) -> 2-way banks on A-frag reads.
// Fragments converted in-register via v_cvt_pk_bf16_f32 (RNE, same numerics
// as the old standalone cast). Swapped-operand MFMA (acc = C^T) -> packed
// ushort4 stores for q/k. XCD-aware 1D grid swizzle (1152 % 8 == 0).
template<int NX>
__global__ __launch_bounds__(256) void gemm_qkv(
        const float* __restrict__ X, const u16* __restrict__ Bt,
        const float* __restrict__ bias,
        u16* __restrict__ qb, u16* __restrict__ kb, u16* __restrict__ vtb,
        int K) {
    __shared__ float sA[2][128 * 32];   // fp32, slot-swizzled
    __shared__ u16   sB[2][128 * 32];   // bf16, linear
    const int tid = threadIdx.x;
    const int lane = tid & 63;
    const int w = tid >> 6;
    const int wr = w >> 1, wc = w & 1;          // 64x64 quadrant per wave
    const int g = lane >> 4;
    const int cpx = gridDim.x >> 3;
    const int wg = ((int)blockIdx.x & 7) * cpx + ((int)blockIdx.x >> 3);
    const int bx = wg % NX, by = wg / NX;
    const int m0 = by * 128, n0 = bx * 128;

    f32x4 acc[4][4] = {};

    // A: 128 rows x 32 floats (128 B = 8 slots of 16 B) = 1024 chunks.
    // phys slot p at row r holds logical slot l = p ^ (r & 7).
    auto stage = [&](int buf, int kt) {
        #pragma unroll
        for (int i = 0; i < 4; ++i) {
            int c = i * 256 + tid;
            int r = c >> 3, p = c & 7;
            int l = p ^ (r & 7);
            gload_lds(X + (size_t)(m0 + r) * K + kt * 32 + l * 4, &sA[buf][c * 4]);
        }
        #pragma unroll
        for (int i = 0; i < 2; ++i) {
            int c = i * 256 + tid;
            int row = c >> 2, c8 = c & 3;
            gload_lds(Bt + (size_t)(n0 + row) * K + kt * 32 + c8 * 8, &sB[buf][c * 8]);
        }
    };

    const int KT = K / 32;                      // 24
    stage(0, 0);
    __syncthreads();
    for (int kt = 0; kt < KT; ++kt) {
        if (kt + 1 < KT) stage((kt + 1) & 1, kt + 1);   // overlaps compute(kt)
        const float* cA = sA[kt & 1];
        const u16*  cB = sB[kt & 1];
        bf16x8 af[4], bfr[4];
        #pragma unroll
        for (int m = 0; m < 4; ++m) {
            int r = wr * 64 + m * 16 + (lane & 15);
            float4 a0 = *(const float4*)&cA[r * 32 + (((2 * g)     ^ (r & 7)) << 2)];
            float4 a1 = *(const float4*)&cA[r * 32 + (((2 * g + 1) ^ (r & 7)) << 2)];
            union { unsigned u[4]; bf16x8 v; } t;
            t.u[0] = cvtpk(a0.x, a0.y);
            t.u[1] = cvtpk(a0.z, a0.w);
            t.u[2] = cvtpk(a1.x, a1.y);
            t.u[3] = cvtpk(a1.z, a1.w);
            af[m] = t.v;
        }
        #pragma unroll
        for (int n = 0; n < 4; ++n)
            bfr[n] = *(const bf16x8*)&cB[(wc * 64 + n * 16 + (lane & 15)) * 32 + (g << 3)];
        __builtin_amdgcn_s_setprio(1);
        #pragma unroll
        for (int m = 0; m < 4; ++m)
            #pragma unroll
            for (int n = 0; n < 4; ++n)
                acc[m][n] = MFMA16(bfr[n], af[m], acc[m][n]);   // C^T tile
        __builtin_amdgcn_s_setprio(0);
        __syncthreads();
    }

    // Epilogue: D row = channel (wc*64 + n*16 + g*4 + j), D col = token
    const int which = n0 / CDIM;                // 0=q 1=k 2=v, uniform per block
    #pragma unroll
    for (int m = 0; m < 4; ++m) {
        const int rg = m0 + wr * 64 + m * 16 + (lane & 15);
        const int b = rg >> 11, t = rg & (TSEQ - 1);
        #pragma unroll
        for (int n = 0; n < 4; ++n) {
            const int cg = n0 + wc * 64 + n * 16 + (g << 2);
            const int c  = cg - which * CDIM;
            const int h  = c >> 6, d = c & 63;
            const size_t bh = (size_t)(b * HNUM + h);
            const float4 bv = *(const float4*)&bias[cg];
            const float v0 = acc[m][n][0] + bv.x;
            const float v1 = acc[m][n][1] + bv.y;
            const float v2 = acc[m][n][2] + bv.z;
            const float v3 = acc[m][n][3] + bv.w;
            if (which == 0) {
                const float s = 0.1803368801111243f;   // 0.125 * log2(e)
                ushort4 pv;
                pv.x = f2b(v0 * s); pv.y = f2b(v1 * s);
                pv.z = f2b(v2 * s); pv.w = f2b(v3 * s);
                *(ushort4*)&qb[(bh * TSEQ + t) * DHEAD + d] = pv;
            } else if (which == 1) {
                ushort4 pv;
                pv.x = f2b(v0); pv.y = f2b(v1); pv.z = f2b(v2); pv.w = f2b(v3);
                *(ushort4*)&kb[(bh * TSEQ + t) * DHEAD + d] = pv;
            } else {
                vtb[(bh * DHEAD + d + 0) * TSEQ + t] = f2b(v0);
                vtb[(bh * DHEAD + d + 1) * TSEQ + t] = f2b(v1);
                vtb[(bh * DHEAD + d + 2) * TSEQ + t] = f2b(v2);
                vtb[(bh * DHEAD + d + 3) * TSEQ + t] = f2b(v3);
            }
        }
    }
}

// ---------------- GEMM2: out projection (R8 3-ring kernel, unchanged) -------
template<int NX>
__global__ __launch_bounds__(256) void gemm_out(
        const u16* __restrict__ A, const u16* __restrict__ Bt,
        const float* __restrict__ bias, float* __restrict__ outf, int K) {
    __shared__ u16 sA[3][128 * 32];
    __shared__ u16 sB[3][128 * 32];
    const int tid = threadIdx.x;
    const int lane = tid & 63;
    const int w = tid >> 6;
    const int wr = w >> 1, wc = w & 1;
    const int cpx = gridDim.x >> 3;
    const int wg = ((int)blockIdx.x & 7) * cpx + ((int)blockIdx.x >> 3);
    const int bx = wg % NX, by = wg / NX;
    const int m0 = by * 128, n0 = bx * 128;

    f32x4 acc[4][4] = {};

    auto stage = [&](int buf, int kt) {
        #pragma unroll
        for (int i = 0; i < 2; ++i) {
            int chunk = i * 256 + tid;
            int row = chunk >> 2, c8 = chunk & 3;
            gload_lds(A  + (size_t)(m0 + row) * K + kt * 32 + c8 * 8, &sA[buf][chunk * 8]);
            gload_lds(Bt + (size_t)(n0 + row) * K + kt * 32 + c8 * 8, &sB[buf][chunk * 8]);
        }
    };

    const int KT = K / 32;
    stage(0, 0); stage(1, 1);
    for (int kt = 0; kt < KT; ++kt) {
        if (kt + 1 < KT) asm volatile("s_waitcnt vmcnt(4)" ::: "memory");
        else             asm volatile("s_waitcnt vmcnt(0)" ::: "memory");
        __builtin_amdgcn_s_barrier();
        if (kt + 2 < KT) stage((kt + 2) % 3, kt + 2);
        const u16* cA = sA[kt % 3];
        const u16* cB = sB[kt % 3];
        bf16x8 af[4], bfr[4];
        #pragma unroll
        for (int m = 0; m < 4; ++m)
            af[m] = *(const bf16x8*)&cA[(wr * 64 + m * 16 + (lane & 15)) * 32 + ((lane >> 4) << 3)];
        #pragma unroll
        for (int n = 0; n < 4; ++n)
            bfr[n] = *(const bf16x8*)&cB[(wc * 64 + n * 16 + (lane & 15)) * 32 + ((lane >> 4) << 3)];
        #pragma unroll
        for (int m = 0; m < 4; ++m)
            #pragma unroll
            for (int n = 0; n < 4; ++n)
                acc[m][n] = MFMA16(bfr[n], af[m], acc[m][n]);   // C^T tile
    }

    #pragma unroll
    for (int m = 0; m < 4; ++m) {
        const int rg = m0 + wr * 64 + m * 16 + (lane & 15);
        #pragma unroll
        for (int n = 0; n < 4; ++n) {
            const int cg = n0 + wc * 64 + n * 16 + ((lane >> 4) << 2);
            const float4 bv = *(const float4*)&bias[cg];
            float4 ov;
            ov.x = acc[m][n][0] + bv.x;
            ov.y = acc[m][n][1] + bv.y;
            ov.z = acc[m][n][2] + bv.z;
            ov.w = acc[m][n][3] + bv.w;
            *(float4*)&outf[(size_t)rg * CDIM + cg] = ov;
        }
    }
}

// ---------------- causal flash attention (R8 kernel, unchanged) --------------
__global__ __launch_bounds__(256, 4) void attn_fwd(
        const u16* __restrict__ qb, const u16* __restrict__ kb,
        const u16* __restrict__ vtb, u16* __restrict__ yb) {
    __shared__ u16 sK[2][64 * 64];
    __shared__ u16 sVt[2][64 * 64];
    const int qt = 31 - (int)(blockIdx.x / BH);  // 64-row q-tile, longest first
    const int bh = blockIdx.x % BH;
    const int b = bh / HNUM, h = bh % HNUM;
    const int tid = threadIdx.x, lane = tid & 63, w = tid >> 6;   // w 0..3
    const int g = lane >> 4, lq = lane & 15;
    const int qlo = qt * 64 + w * 16;            // wave's 16 q rows
    const u16* qbase = qb  + (size_t)bh * TSEQ * DHEAD;
    const u16* kbase = kb  + (size_t)bh * TSEQ * DHEAD;
    const u16* vbase = vtb + (size_t)bh * DHEAD * TSEQ;

    // Q fragment (B-operand): Q[qlo+lq][ks*32 + g*8 + e] (scale pre-folded)
    bf16x8 qf[2];
    #pragma unroll
    for (int ks = 0; ks < 2; ++ks)
        qf[ks] = *(const bf16x8*)&qbase[(size_t)(qlo + lq) * DHEAD + ks * 32 + g * 8];

    // all-ones bf16 B-fragment for the row-sum MFMA
    union { unsigned u[4]; bf16x8 v; } ones;
    #pragma unroll
    for (int i = 0; i < 4; ++i) ones.u[i] = 0x3f803f80u;

    f32x4 o[4] = {};
    f32x4 ls = {};                               // row sums, O-layout (q=g*4+j)
    float mx = -__builtin_inff();

    // staging: 2 chunks of K + 2 of Vt per thread (swizzled source, linear dest)
    auto STAGE = [&](int buf, int kt) {
        const int k0 = kt << 6;
        #pragma unroll
        for (int i = 0; i < 2; ++i) {
            int chunk = i * 256 + tid;           // 512 chunks of 16B per tile
            int srow = chunk >> 3;
            int cb = ((chunk & 7) << 4) ^ ((srow & 7) << 4);   // logical byte col
            gload_lds(kbase + (size_t)(k0 + srow) * DHEAD + (cb >> 1), &sK[buf][chunk * 8]);
            gload_lds(vbase + (size_t)srow * TSEQ + k0 + (cb >> 1),    &sVt[buf][chunk * 8]);
        }
    };

    const int nk = qt + 1;
    STAGE(0, 0);
    __syncthreads();
    for (int kt = 0; kt < nk; ++kt) {
        const int k0 = kt << 6;
        if (kt + 1 < nk) STAGE((kt + 1) & 1, kt + 1);   // prefetch overlaps compute
        const u16* cK = sK[kt & 1];
        const u16* cV = sVt[kt & 1];
        // S^T = K Q^T : lane holds q=lq, kpos = k0 + n*16 + g*4 + j
        f32x4 s[4];
        #pragma unroll
        for (int n = 0; n < 4; ++n) s[n] = f32x4{0.f, 0.f, 0.f, 0.f};
        __builtin_amdgcn_s_setprio(1);
        #pragma unroll
        for (int n = 0; n < 4; ++n) {
            #pragma unroll
            for (int ks = 0; ks < 2; ++ks) {
                int r = n * 16 + lq;
                int lb = (r * 128 + (ks * 32 + g * 8) * 2) ^ ((r & 7) << 4);
                bf16x8 kf = *(const bf16x8*)((const char*)cK + lb);
                s[n] = MFMA16(kf, qf[ks], s[n]);
            }
        }
        __builtin_amdgcn_s_setprio(0);
        // causal mask (only near-diagonal tiles)
        if (k0 + 63 > qlo) {
            const int qa = qlo + lq;
            #pragma unroll
            for (int n = 0; n < 4; ++n)
                #pragma unroll
                for (int j = 0; j < 4; ++j)
                    if (k0 + n * 16 + g * 4 + j > qa) s[n][j] = -__builtin_inff();
        }
        // row max (row q=lq): 15 in-lane + 2 cross-group shfls
        float t0 = fmaxf(fmaxf(s[0][0], s[0][1]), fmaxf(s[0][2], s[0][3]));
        float t1 = fmaxf(fmaxf(s[1][0], s[1][1]), fmaxf(s[1][2], s[1][3]));
        float t2 = fmaxf(fmaxf(s[2][0], s[2][1]), fmaxf(s[2][2], s[2][3]));
        float t3 = fmaxf(fmaxf(s[3][0], s[3][1]), fmaxf(s[3][2], s[3][3]));
        float tmax = fmaxf(fmaxf(t0, t1), fmaxf(t2, t3));
        tmax = fmaxf(tmax, __shfl_xor(tmax, 16));
        tmax = fmaxf(tmax, __shfl_xor(tmax, 32));
        // defer-max: rescale only if some row grew past THR=8 (exp2 units)
        if (__any(tmax > mx + 8.0f)) {
            float mnew = fmaxf(mx, tmax);
            float sc = fexp2(mx - mnew);
            mx = mnew;
            #pragma unroll
            for (int j = 0; j < 4; ++j) {
                float scj = __shfl(sc, (lane & 48) | ((g << 2) + j));
                ls[j] *= scj;
                #pragma unroll
                for (int n = 0; n < 4; ++n) o[n][j] *= scj;
            }
        }
        #pragma unroll
        for (int n = 0; n < 4; ++n)
            #pragma unroll
            for (int j = 0; j < 4; ++j)
                s[n][j] = fexp2(s[n][j] - mx);
        // pack P to bf16 pairs (k ascending within u32)
        unsigned apk[4], bpk[4];
        #pragma unroll
        for (int n = 0; n < 4; ++n) {
            apk[n] = cvtpk(s[n][0], s[n][1]);
            bpk[n] = cvtpk(s[n][2], s[n][3]);
        }
        // PV: redistribute P into A-frag layout via shfl, then MFMA.
        // Row sums ride the matrix pipe: ls += pa * ones.
        const int s0l = lq + ((lane & 16) << 1);
        const bool hi = (lane & 32) != 0;
        #pragma unroll
        for (int ks = 0; ks < 2; ++ks) {
            unsigned A0  = (unsigned)__shfl((int)apk[2 * ks],     s0l);
            unsigned B0  = (unsigned)__shfl((int)bpk[2 * ks],     s0l);
            unsigned A1  = (unsigned)__shfl((int)apk[2 * ks + 1], s0l);
            unsigned B1  = (unsigned)__shfl((int)bpk[2 * ks + 1], s0l);
            unsigned A0h = (unsigned)__shfl((int)apk[2 * ks],     s0l + 16);
            unsigned B0h = (unsigned)__shfl((int)bpk[2 * ks],     s0l + 16);
            unsigned A1h = (unsigned)__shfl((int)apk[2 * ks + 1], s0l + 16);
            unsigned B1h = (unsigned)__shfl((int)bpk[2 * ks + 1], s0l + 16);
            union { unsigned u[4]; bf16x8 v; } pa;
            pa.u[0] = hi ? A1  : A0;
            pa.u[1] = hi ? B1  : B0;
            pa.u[2] = hi ? A1h : A0h;
            pa.u[3] = hi ? B1h : B0h;
            __builtin_amdgcn_s_setprio(1);
            #pragma unroll
            for (int n = 0; n < 4; ++n) {
                int d = n * 16 + lq;
                int lb = (d * 128 + (ks * 32 + g * 8) * 2) ^ ((d & 7) << 4);
                bf16x8 vf = *(const bf16x8*)((const char*)cV + lb);
                o[n] = MFMA16(pa.v, vf, o[n]);
            }
            ls = MFMA16(pa.v, ones.v, ls);
            __builtin_amdgcn_s_setprio(0);
        }
        __syncthreads();
    }

    // epilogue: y[b, t, h*64 + d] bf16 ; O rows q = g*4+j; ls already O-layout
    #pragma unroll
    for (int j = 0; j < 4; ++j) {
        float inv = 1.f / ls[j];
        const int t = qlo + g * 4 + j;
        #pragma unroll
        for (int n = 0; n < 4; ++n) {
            const int c = h * DHEAD + n * 16 + lq;
            yb[((size_t)b * TSEQ + t) * CDIM + c] = f2b(o[n][j] * inv);
        }
    }
}

extern "C" void kernel_launch(void* const* d_in, const int* in_sizes, int n_in,
                              void* d_out, int out_size, void* d_ws, size_t ws_size,
                              hipStream_t stream) {
    const float* x      = (const float*)d_in[0];
    const float* W_attn = (const float*)d_in[1];
    const float* b_attn = (const float*)d_in[2];
    const float* W_proj = (const float*)d_in[3];
    const float* b_proj = (const float*)d_in[4];
    float* out = (float*)d_out;

    // workspace layout (bf16 = u16)
    u16* ws = (u16*)d_ws;
    u16* yb     = ws;                                   // [BTOT][CDIM] attn out
    u16* WattnT = yb     + (size_t)BTOT * CDIM;         // [NQKV][CDIM]
    u16* WprojT = WattnT + (size_t)NQKV * CDIM;         // [CDIM][CDIM]
    u16* qb     = WprojT + (size_t)CDIM * CDIM;         // [BH][TSEQ][DHEAD]
    u16* kb     = qb     + (size_t)BH * TSEQ * DHEAD;
    u16* vtb    = kb     + (size_t)BH * TSEQ * DHEAD;   // [BH][DHEAD][TSEQ]

    // 1) weight transposes (single launch covers both)
    tcast2<<<dim3(NQKV / 32 + CDIM / 32, CDIM / 32), dim3(32, 8), 0, stream>>>(
        W_attn, W_proj, WattnT, WprojT);

    // 2) QKV projection with fused x-cast (1152 blocks, XCD-swizzled)
    gemm_qkv<NQKV / 128><<<dim3((NQKV / 128) * (BTOT / 128)), 256, 0, stream>>>(
        x, WattnT, b_attn, qb, kb, vtb, CDIM);

    // 3) causal flash attention (fine-grained LPT: 64-row q-tiles, longest first)
    attn_fwd<<<dim3((TSEQ / 64) * BH), 256, 0, stream>>>(qb, kb, vtb, yb);

    // 4) output projection (384 blocks, XCD-swizzled)
    gemm_out<CDIM / 128><<<dim3((CDIM / 128) * (BTOT / 128)), 256, 0, stream>>>(
        yb, WprojT, b_proj, out, CDIM);
}

// Round 11
// 141.664 us; speedup vs baseline: 1.0754x; 1.0058x over previous
//
#include <hip/hip_runtime.h>
#include <hip/hip_bf16.h>

// Problem constants
#define BATCH 4
#define TSEQ  2048
#define CDIM  768
#define HNUM  12
#define DHEAD 64
#define NQKV  (3*CDIM)          // 2304
#define BTOT  (BATCH*TSEQ)      // 8192
#define BH    (BATCH*HNUM)      // 48

typedef unsigned short u16;
typedef __attribute__((ext_vector_type(8))) __bf16 bf16x8;
typedef __attribute__((ext_vector_type(4))) float f32x4;

#define MFMA16(a,b,c) __builtin_amdgcn_mfma_f32_16x16x32_bf16((a),(b),(c),0,0,0)

// fp32 -> bf16 RNE (hand-rolled, version-independent)
__device__ __forceinline__ u16 f2b(float f) {
    union { float f; unsigned u; } v; v.f = f;
    unsigned u = v.u;
    unsigned r = (u + 0x7fffu + ((u >> 16) & 1u)) >> 16;
    return (u16)r;
}

// pack 2 fp32 -> 2 bf16 in one u32 (lo -> bits 15:0), RNE
__device__ __forceinline__ unsigned cvtpk(float lo, float hi) {
    unsigned r;
    asm("v_cvt_pk_bf16_f32 %0, %1, %2" : "=v"(r) : "v"(lo), "v"(hi));
    return r;
}

// raw 2^x
__device__ __forceinline__ float fexp2(float x) {
    float r;
    asm("v_exp_f32 %0, %1" : "=v"(r) : "v"(x));
    return r;
}

__device__ __forceinline__ void gload_lds(const void* g, void* l) {
    __builtin_amdgcn_global_load_lds(
        (const __attribute__((address_space(1))) void*)g,
        (__attribute__((address_space(3))) void*)l, 16, 0, 0);
}

// ---------------- elementwise cast fp32 -> bf16 ----------------
__global__ __launch_bounds__(256) void cast_f32_bf16(
        const float* __restrict__ in, u16* __restrict__ out, int n4) {
    int i = blockIdx.x * blockDim.x + threadIdx.x;
    if (i >= n4) return;
    float4 a = reinterpret_cast<const float4*>(in)[i];
    ushort4 o;
    o.x = f2b(a.x); o.y = f2b(a.y); o.z = f2b(a.z); o.w = f2b(a.w);
    reinterpret_cast<ushort4*>(out)[i] = o;
}

// ---------------- weight transpose+cast (both weights, one launch) ----------
__global__ __launch_bounds__(256) void tcast2(
        const float* __restrict__ Wa, const float* __restrict__ Wp,
        u16* __restrict__ WaT, u16* __restrict__ WpT) {
    __shared__ float tile[32][33];
    const float* in; u16* out; int Cc; int bx = blockIdx.x;
    if (bx < NQKV / 32) { in = Wa; out = WaT; Cc = NQKV; }
    else                { in = Wp; out = WpT; Cc = CDIM; bx -= NQKV / 32; }
    int c0 = bx * 32, r0 = blockIdx.y * 32;
    int tx = threadIdx.x, ty = threadIdx.y;   // block (32,8)
    #pragma unroll
    for (int i = 0; i < 32; i += 8)
        tile[ty + i][tx] = in[(size_t)(r0 + ty + i) * Cc + c0 + tx];
    __syncthreads();
    #pragma unroll
    for (int i = 0; i < 32; i += 8)
        out[(size_t)(c0 + ty + i) * CDIM + r0 + tx] = f2b(tile[tx][ty + i]);
}

// ---------------- GEMM: C[M x N] = A[M x K] * Bt[N x K]^T (+bias) ----------------
// R6 cadence (2-buf, stage(kt+1) -> compute(kt) -> syncthreads) + 4-slot XOR
// swizzle s^((r>>1)&3) on BOTH tiles, BOTH sides (pre-swizzled gload source,
// fragment reads XOR the same involution) -> bank conflicts ~0 (verified R9).
// Swapped-operand MFMA (acc = C^T tile) -> packed ushort4/float4 stores.
// XCD-aware 1D grid swizzle. MODE 0 scatters q (0.125*log2e folded), k, vT.
template<int MODE, int NX>
__global__ __launch_bounds__(256) void gemm_bt(
        const u16* __restrict__ A, const u16* __restrict__ Bt,
        const float* __restrict__ bias,
        u16* __restrict__ qb, u16* __restrict__ kb, u16* __restrict__ vtb,
        float* __restrict__ outf, int K) {
    __shared__ u16 sA[2][128 * 32];
    __shared__ u16 sB[2][128 * 32];
    const int tid = threadIdx.x;
    const int lane = tid & 63;
    const int w = tid >> 6;
    const int wr = w >> 1, wc = w & 1;          // 64x64 quadrant per wave
    const int g = lane >> 4, lq = lane & 15;
    const int cpx = gridDim.x >> 3;
    const int wg = ((int)blockIdx.x & 7) * cpx + ((int)blockIdx.x >> 3);
    const int bx = wg % NX, by = wg / NX;
    const int m0 = by * 128, n0 = bx * 128;

    f32x4 acc[4][4] = {};

    // tile [128][32] u16 = 4 slots of 16B per row; phys slot s holds logical
    // slot s ^ ((r>>1)&3).
    auto stage = [&](int buf, int kt) {
        #pragma unroll
        for (int i = 0; i < 2; ++i) {
            int c = i * 256 + tid;              // 512 chunks of 16B
            int r = c >> 2, s = c & 3;
            int l = s ^ ((r >> 1) & 3);
            gload_lds(A  + (size_t)(m0 + r) * K + kt * 32 + l * 8, &sA[buf][c * 8]);
            gload_lds(Bt + (size_t)(n0 + r) * K + kt * 32 + l * 8, &sB[buf][c * 8]);
        }
    };

    const int KT = K / 32;                      // 24
    stage(0, 0);
    __syncthreads();
    for (int kt = 0; kt < KT; ++kt) {
        if (kt + 1 < KT) stage((kt + 1) & 1, kt + 1);   // overlaps compute(kt)
        const u16* cA = sA[kt & 1];
        const u16* cB = sB[kt & 1];
        bf16x8 af[4], bfr[4];
        #pragma unroll
        for (int m = 0; m < 4; ++m) {
            int r = wr * 64 + m * 16 + lq;
            af[m] = *(const bf16x8*)&cA[r * 32 + ((g ^ ((r >> 1) & 3)) << 3)];
        }
        #pragma unroll
        for (int n = 0; n < 4; ++n) {
            int r = wc * 64 + n * 16 + lq;
            bfr[n] = *(const bf16x8*)&cB[r * 32 + ((g ^ ((r >> 1) & 3)) << 3)];
        }
        __builtin_amdgcn_s_setprio(1);
        #pragma unroll
        for (int m = 0; m < 4; ++m)
            #pragma unroll
            for (int n = 0; n < 4; ++n)
                acc[m][n] = MFMA16(bfr[n], af[m], acc[m][n]);   // C^T tile
        __builtin_amdgcn_s_setprio(0);
        __syncthreads();
    }

    // Epilogue. D row = channel (wc*64 + n*16 + g*4 + j), D col = token
    if (MODE == 0) {
        const int which = n0 / CDIM;            // 0=q 1=k 2=v, uniform per block
        #pragma unroll
        for (int m = 0; m < 4; ++m) {
            const int rg = m0 + wr * 64 + m * 16 + lq;
            const int b = rg >> 11, t = rg & (TSEQ - 1);
            #pragma unroll
            for (int n = 0; n < 4; ++n) {
                const int cg = n0 + wc * 64 + n * 16 + (g << 2);
                const int c  = cg - which * CDIM;
                const int h  = c >> 6, d = c & 63;
                const size_t bh = (size_t)(b * HNUM + h);
                const float4 bv = *(const float4*)&bias[cg];
                const float v0 = acc[m][n][0] + bv.x;
                const float v1 = acc[m][n][1] + bv.y;
                const float v2 = acc[m][n][2] + bv.z;
                const float v3 = acc[m][n][3] + bv.w;
                if (which == 0) {
                    const float s = 0.1803368801111243f;   // 0.125 * log2(e)
                    ushort4 pv;
                    pv.x = f2b(v0 * s); pv.y = f2b(v1 * s);
                    pv.z = f2b(v2 * s); pv.w = f2b(v3 * s);
                    *(ushort4*)&qb[(bh * TSEQ + t) * DHEAD + d] = pv;
                } else if (which == 1) {
                    ushort4 pv;
                    pv.x = f2b(v0); pv.y = f2b(v1); pv.z = f2b(v2); pv.w = f2b(v3);
                    *(ushort4*)&kb[(bh * TSEQ + t) * DHEAD + d] = pv;
                } else {
                    vtb[(bh * DHEAD + d + 0) * TSEQ + t] = f2b(v0);
                    vtb[(bh * DHEAD + d + 1) * TSEQ + t] = f2b(v1);
                    vtb[(bh * DHEAD + d + 2) * TSEQ + t] = f2b(v2);
                    vtb[(bh * DHEAD + d + 3) * TSEQ + t] = f2b(v3);
                }
            }
        }
    } else {
        #pragma unroll
        for (int m = 0; m < 4; ++m) {
            const int rg = m0 + wr * 64 + m * 16 + lq;
            #pragma unroll
            for (int n = 0; n < 4; ++n) {
                const int cg = n0 + wc * 64 + n * 16 + (g << 2);
                const float4 bv = *(const float4*)&bias[cg];
                float4 ov;
                ov.x = acc[m][n][0] + bv.x;
                ov.y = acc[m][n][1] + bv.y;
                ov.z = acc[m][n][2] + bv.z;
                ov.w = acc[m][n][3] + bv.w;
                *(float4*)&outf[(size_t)rg * CDIM + cg] = ov;
            }
        }
    }
}

// ---------------- causal flash attention (R8 kernel, unchanged) --------------
__global__ __launch_bounds__(256, 4) void attn_fwd(
        const u16* __restrict__ qb, const u16* __restrict__ kb,
        const u16* __restrict__ vtb, u16* __restrict__ yb) {
    __shared__ u16 sK[2][64 * 64];
    __shared__ u16 sVt[2][64 * 64];
    const int qt = 31 - (int)(blockIdx.x / BH);  // 64-row q-tile, longest first
    const int bh = blockIdx.x % BH;
    const int b = bh / HNUM, h = bh % HNUM;
    const int tid = threadIdx.x, lane = tid & 63, w = tid >> 6;   // w 0..3
    const int g = lane >> 4, lq = lane & 15;
    const int qlo = qt * 64 + w * 16;            // wave's 16 q rows
    const u16* qbase = qb  + (size_t)bh * TSEQ * DHEAD;
    const u16* kbase = kb  + (size_t)bh * TSEQ * DHEAD;
    const u16* vbase = vtb + (size_t)bh * DHEAD * TSEQ;

    // Q fragment (B-operand): Q[qlo+lq][ks*32 + g*8 + e] (scale pre-folded)
    bf16x8 qf[2];
    #pragma unroll
    for (int ks = 0; ks < 2; ++ks)
        qf[ks] = *(const bf16x8*)&qbase[(size_t)(qlo + lq) * DHEAD + ks * 32 + g * 8];

    // all-ones bf16 B-fragment for the row-sum MFMA
    union { unsigned u[4]; bf16x8 v; } ones;
    #pragma unroll
    for (int i = 0; i < 4; ++i) ones.u[i] = 0x3f803f80u;

    f32x4 o[4] = {};
    f32x4 ls = {};                               // row sums, O-layout (q=g*4+j)
    float mx = -__builtin_inff();

    // staging: 2 chunks of K + 2 of Vt per thread (swizzled source, linear dest)
    auto STAGE = [&](int buf, int kt) {
        const int k0 = kt << 6;
        #pragma unroll
        for (int i = 0; i < 2; ++i) {
            int chunk = i * 256 + tid;           // 512 chunks of 16B per tile
            int srow = chunk >> 3;
            int cb = ((chunk & 7) << 4) ^ ((srow & 7) << 4);   // logical byte col
            gload_lds(kbase + (size_t)(k0 + srow) * DHEAD + (cb >> 1), &sK[buf][chunk * 8]);
            gload_lds(vbase + (size_t)srow * TSEQ + k0 + (cb >> 1),    &sVt[buf][chunk * 8]);
        }
    };

    const int nk = qt + 1;
    STAGE(0, 0);
    __syncthreads();
    for (int kt = 0; kt < nk; ++kt) {
        const int k0 = kt << 6;
        if (kt + 1 < nk) STAGE((kt + 1) & 1, kt + 1);   // prefetch overlaps compute
        const u16* cK = sK[kt & 1];
        const u16* cV = sVt[kt & 1];
        // S^T = K Q^T : lane holds q=lq, kpos = k0 + n*16 + g*4 + j
        f32x4 s[4];
        #pragma unroll
        for (int n = 0; n < 4; ++n) s[n] = f32x4{0.f, 0.f, 0.f, 0.f};
        __builtin_amdgcn_s_setprio(1);
        #pragma unroll
        for (int n = 0; n < 4; ++n) {
            #pragma unroll
            for (int ks = 0; ks < 2; ++ks) {
                int r = n * 16 + lq;
                int lb = (r * 128 + (ks * 32 + g * 8) * 2) ^ ((r & 7) << 4);
                bf16x8 kf = *(const bf16x8*)((const char*)cK + lb);
                s[n] = MFMA16(kf, qf[ks], s[n]);
            }
        }
        __builtin_amdgcn_s_setprio(0);
        // causal mask (only near-diagonal tiles)
        if (k0 + 63 > qlo) {
            const int qa = qlo + lq;
            #pragma unroll
            for (int n = 0; n < 4; ++n)
                #pragma unroll
                for (int j = 0; j < 4; ++j)
                    if (k0 + n * 16 + g * 4 + j > qa) s[n][j] = -__builtin_inff();
        }
        // row max (row q=lq): 15 in-lane + 2 cross-group shfls
        float t0 = fmaxf(fmaxf(s[0][0], s[0][1]), fmaxf(s[0][2], s[0][3]));
        float t1 = fmaxf(fmaxf(s[1][0], s[1][1]), fmaxf(s[1][2], s[1][3]));
        float t2 = fmaxf(fmaxf(s[2][0], s[2][1]), fmaxf(s[2][2], s[2][3]));
        float t3 = fmaxf(fmaxf(s[3][0], s[3][1]), fmaxf(s[3][2], s[3][3]));
        float tmax = fmaxf(fmaxf(t0, t1), fmaxf(t2, t3));
        tmax = fmaxf(tmax, __shfl_xor(tmax, 16));
        tmax = fmaxf(tmax, __shfl_xor(tmax, 32));
        // defer-max: rescale only if some row grew past THR=8 (exp2 units)
        if (__any(tmax > mx + 8.0f)) {
            float mnew = fmaxf(mx, tmax);
            float sc = fexp2(mx - mnew);
            mx = mnew;
            #pragma unroll
            for (int j = 0; j < 4; ++j) {
                float scj = __shfl(sc, (lane & 48) | ((g << 2) + j));
                ls[j] *= scj;
                #pragma unroll
                for (int n = 0; n < 4; ++n) o[n][j] *= scj;
            }
        }
        #pragma unroll
        for (int n = 0; n < 4; ++n)
            #pragma unroll
            for (int j = 0; j < 4; ++j)
                s[n][j] = fexp2(s[n][j] - mx);
        // pack P to bf16 pairs (k ascending within u32)
        unsigned apk[4], bpk[4];
        #pragma unroll
        for (int n = 0; n < 4; ++n) {
            apk[n] = cvtpk(s[n][0], s[n][1]);
            bpk[n] = cvtpk(s[n][2], s[n][3]);
        }
        // PV: redistribute P into A-frag layout via shfl, then MFMA.
        // Row sums ride the matrix pipe: ls += pa * ones.
        const int s0l = lq + ((lane & 16) << 1);
        const bool hi = (lane & 32) != 0;
        #pragma unroll
        for (int ks = 0; ks < 2; ++ks) {
            unsigned A0  = (unsigned)__shfl((int)apk[2 * ks],     s0l);
            unsigned B0  = (unsigned)__shfl((int)bpk[2 * ks],     s0l);
            unsigned A1  = (unsigned)__shfl((int)apk[2 * ks + 1], s0l);
            unsigned B1  = (unsigned)__shfl((int)bpk[2 * ks + 1], s0l);
            unsigned A0h = (unsigned)__shfl((int)apk[2 * ks],     s0l + 16);
            unsigned B0h = (unsigned)__shfl((int)bpk[2 * ks],     s0l + 16);
            unsigned A1h = (unsigned)__shfl((int)apk[2 * ks + 1], s0l + 16);
            unsigned B1h = (unsigned)__shfl((int)bpk[2 * ks + 1], s0l + 16);
            union { unsigned u[4]; bf16x8 v; } pa;
            pa.u[0] = hi ? A1  : A0;
            pa.u[1] = hi ? B1  : B0;
            pa.u[2] = hi ? A1h : A0h;
            pa.u[3] = hi ? B1h : B0h;
            __builtin_amdgcn_s_setprio(1);
            #pragma unroll
            for (int n = 0; n < 4; ++n) {
                int d = n * 16 + lq;
                int lb = (d * 128 + (ks * 32 + g * 8) * 2) ^ ((d & 7) << 4);
                bf16x8 vf = *(const bf16x8*)((const char*)cV + lb);
                o[n] = MFMA16(pa.v, vf, o[n]);
            }
            ls = MFMA16(pa.v, ones.v, ls);
            __builtin_amdgcn_s_setprio(0);
        }
        __syncthreads();
    }

    // epilogue: y[b, t, h*64 + d] bf16 ; O rows q = g*4+j; ls already O-layout
    #pragma unroll
    for (int j = 0; j < 4; ++j) {
        float inv = 1.f / ls[j];
        const int t = qlo + g * 4 + j;
        #pragma unroll
        for (int n = 0; n < 4; ++n) {
            const int c = h * DHEAD + n * 16 + lq;
            yb[((size_t)b * TSEQ + t) * CDIM + c] = f2b(o[n][j] * inv);
        }
    }
}

extern "C" void kernel_launch(void* const* d_in, const int* in_sizes, int n_in,
                              void* d_out, int out_size, void* d_ws, size_t ws_size,
                              hipStream_t stream) {
    const float* x      = (const float*)d_in[0];
    const float* W_attn = (const float*)d_in[1];
    const float* b_attn = (const float*)d_in[2];
    const float* W_proj = (const float*)d_in[3];
    const float* b_proj = (const float*)d_in[4];
    float* out = (float*)d_out;

    // workspace layout (bf16 = u16). yb aliases xb (xb dead after GEMM1).
    u16* ws = (u16*)d_ws;
    u16* xb     = ws;                                   // [BTOT][CDIM]
    u16* yb     = xb;                                   // [BTOT][CDIM] (alias)
    u16* WattnT = xb     + (size_t)BTOT * CDIM;         // [NQKV][CDIM]
    u16* WprojT = WattnT + (size_t)NQKV * CDIM;         // [CDIM][CDIM]
    u16* qb     = WprojT + (size_t)CDIM * CDIM;         // [BH][TSEQ][DHEAD]
    u16* kb     = qb     + (size_t)BH * TSEQ * DHEAD;
    u16* vtb    = kb     + (size_t)BH * TSEQ * DHEAD;   // [BH][DHEAD][TSEQ]

    // 1) casts / transposes
    int n4 = BTOT * CDIM / 4;
    cast_f32_bf16<<<(n4 + 255) / 256, 256, 0, stream>>>(x, xb, n4);
    tcast2<<<dim3(NQKV / 32 + CDIM / 32, CDIM / 32), dim3(32, 8), 0, stream>>>(
        W_attn, W_proj, WattnT, WprojT);

    // 2) QKV projection + scatter (1152 blocks, XCD-swizzled, conflict-free LDS)
    gemm_bt<0, NQKV / 128><<<dim3((NQKV / 128) * (BTOT / 128)), 256, 0, stream>>>(
        xb, WattnT, b_attn, qb, kb, vtb, nullptr, CDIM);

    // 3) causal flash attention (fine-grained LPT: 64-row q-tiles, longest first)
    attn_fwd<<<dim3((TSEQ / 64) * BH), 256, 0, stream>>>(qb, kb, vtb, yb);

    // 4) output projection (384 blocks, XCD-swizzled, conflict-free LDS)
    gemm_bt<1, CDIM / 128><<<dim3((CDIM / 128) * (BTOT / 128)), 256, 0, stream>>>(
        yb, WprojT, b_proj, nullptr, nullptr, nullptr, out, CDIM);
}